// Round 2
// baseline (124.037 us; speedup 1.0000x reference)
//
#include <hip/hip_runtime.h>
#include <hip/hip_bf16.h>

#define HH 56
#define WW 56
#define HWSZ 3136          // 56*56
#define NB 32              // batch
#define CIN 240
#define MID 60
#define NG 3
#define CING 80            // Cin per group (conv1)
#define MIDG 20            // mid per group
#define COUT 240
#define COUTG 80           // Cout per group (conv3)
#define BN_EPS 1e-5f

// -------- Kernel 1: grouped 1x1 conv (240->60, G=3) + BN1 + ReLU --------
// One thread: one float2 of spatial positions, 5 out-channels (q = quarter) of its group.
// 32*3*4*1568 = 602112 threads = 2352 blocks -> full occupancy; x read exactly once.
__global__ __launch_bounds__(256) void k1_conv1_bn_relu(
        const float* __restrict__ x, const float* __restrict__ w1,
        const float* __restrict__ g1, const float* __restrict__ b1,
        const float* __restrict__ m1, const float* __restrict__ v1,
        float* __restrict__ t1) {
    __shared__ float wlds[MID * CING];   // 4800 floats, layout [co_glob][ci]
    __shared__ float s1[MID], sh1[MID];
    const int tid = threadIdx.x;
    for (int i = tid; i < MID * CING; i += 256) wlds[i] = w1[i];
    if (tid < MID) {
        float inv = g1[tid] * rsqrtf(v1[tid] + BN_EPS);
        s1[tid] = inv;
        sh1[tid] = b1[tid] - m1[tid] * inv;
    }
    __syncthreads();

    const int item = blockIdx.x * 256 + tid;       // < 602112
    const unsigned p2 = (unsigned)item % 1568u;
    unsigned rest = (unsigned)item / 1568u;
    const unsigned q = rest % 4u;  rest /= 4u;
    const unsigned g = rest % 3u;
    const unsigned b = rest / 3u;
    const int pos = (int)p2 * 2;

    const float2* xb = (const float2*)(x + ((size_t)(b * CIN + g * CING)) * HWSZ) + p2;
    // channel stride in float2 units = HWSZ/2 = 1568
    float2 acc[5];
#pragma unroll
    for (int c = 0; c < 5; c++) acc[c] = make_float2(0.f, 0.f);

    const float4* wl4 = (const float4*)wlds;       // [co_glob][ci4], 20 float4 per row
    for (int c4 = 0; c4 < CING / 4; c4++) {
        float2 xv0 = xb[(c4 * 4 + 0) * 1568];
        float2 xv1 = xb[(c4 * 4 + 1) * 1568];
        float2 xv2 = xb[(c4 * 4 + 2) * 1568];
        float2 xv3 = xb[(c4 * 4 + 3) * 1568];
#pragma unroll
        for (int co = 0; co < 5; co++) {
            float4 wv = wl4[(g * MIDG + q * 5 + co) * (CING / 4) + c4];
            acc[co].x += wv.x * xv0.x + wv.y * xv1.x + wv.z * xv2.x + wv.w * xv3.x;
            acc[co].y += wv.x * xv0.y + wv.y * xv1.y + wv.z * xv2.y + wv.w * xv3.y;
        }
    }

#pragma unroll
    for (int co = 0; co < 5; co++) {
        int ch = g * MIDG + q * 5 + co;
        float sc = s1[ch], sf = sh1[ch];
        float2 o;
        o.x = fmaxf(acc[co].x * sc + sf, 0.f);
        o.y = fmaxf(acc[co].y * sc + sf, 0.f);
        *(float2*)(t1 + ((size_t)(b * MID + ch)) * HWSZ + pos) = o;
    }
}

// -------- Kernel 2: depthwise 3x3 (pad 1) + BN2 --------
__global__ __launch_bounds__(256) void k2_dw_bn(
        const float* __restrict__ t1, const float* __restrict__ w2,
        const float* __restrict__ g2, const float* __restrict__ b2,
        const float* __restrict__ m2, const float* __restrict__ v2,
        float* __restrict__ t2) {
    const int item = blockIdx.x * 256 + threadIdx.x;   // < 32*60*784 = 1505280
    const unsigned bc = (unsigned)item / 784u;
    const unsigned p4 = (unsigned)item % 784u;
    const unsigned c = bc % (unsigned)MID;
    const int pos = (int)p4 * 4;
    const int h = pos / WW;
    const int w = pos % WW;                            // w in {0,4,...,52}

    const float* base = t1 + (size_t)bc * HWSZ;
    float k[9];
#pragma unroll
    for (int i = 0; i < 9; i++) k[i] = w2[c * 9 + i];

    float acc0 = 0.f, acc1 = 0.f, acc2 = 0.f, acc3 = 0.f;
#pragma unroll
    for (int dy = -1; dy <= 1; dy++) {
        int r = h + dy;
        if (r < 0 || r >= HH) continue;
        const float* row = base + r * WW + w;
        float4 mid4 = *(const float4*)row;
        float v0 = (w > 0) ? row[-1] : 0.f;
        float v5 = (w + 4 < WW) ? row[4] : 0.f;
        float va[6] = {v0, mid4.x, mid4.y, mid4.z, mid4.w, v5};
        const float k0 = k[(dy + 1) * 3 + 0];
        const float k1 = k[(dy + 1) * 3 + 1];
        const float k2 = k[(dy + 1) * 3 + 2];
        acc0 += k0 * va[0] + k1 * va[1] + k2 * va[2];
        acc1 += k0 * va[1] + k1 * va[2] + k2 * va[3];
        acc2 += k0 * va[2] + k1 * va[3] + k2 * va[4];
        acc3 += k0 * va[3] + k1 * va[4] + k2 * va[5];
    }

    float inv = g2[c] * rsqrtf(v2[c] + BN_EPS);
    float sf = b2[c] - m2[c] * inv;
    float4 o;
    o.x = acc0 * inv + sf;
    o.y = acc1 * inv + sf;
    o.z = acc2 * inv + sf;
    o.w = acc3 * inv + sf;
    *(float4*)(t2 + (size_t)bc * HWSZ + pos) = o;
}

// -------- Kernel 3: channel shuffle (folded) + grouped 1x1 (60->240, G=3)
//          + BN3 + ReLU + residual add --------
// One thread: one float2 of positions, 20 of its group's 80 out-channels (q = quarter).
__global__ __launch_bounds__(256) void k3_shuffle_conv_bn_relu_res(
        const float* __restrict__ t2, const float* __restrict__ w3,
        const float* __restrict__ g3, const float* __restrict__ b3,
        const float* __restrict__ m3, const float* __restrict__ v3,
        const float* __restrict__ x, float* __restrict__ out) {
    __shared__ float wT[NG * MIDG * COUTG];  // [g][ci][co_g] : 4800 floats
    __shared__ float s3[COUT], sh3[COUT];
    const int tid = threadIdx.x;
    for (int i = tid; i < NG * MIDG * COUTG; i += 256) {
        int co_glob = i / MIDG;     // row of w3
        int ci = i % MIDG;
        int gg = co_glob / COUTG;
        int cg = co_glob % COUTG;
        wT[(gg * MIDG + ci) * COUTG + cg] = w3[i];
    }
    if (tid < COUT) {
        float inv = g3[tid] * rsqrtf(v3[tid] + BN_EPS);
        s3[tid] = inv;
        sh3[tid] = b3[tid] - m3[tid] * inv;
    }
    __syncthreads();

    const int item = blockIdx.x * 256 + tid;  // < 32*3*4*1568 = 602112
    const unsigned p2 = (unsigned)item % 1568u;
    unsigned rest = (unsigned)item / 1568u;
    const unsigned q = rest % 4u;  rest /= 4u;
    const unsigned g = rest % 3u;
    const unsigned b = rest / 3u;
    const int pos = (int)p2 * 2;

    float2 acc[MIDG];
#pragma unroll
    for (int c = 0; c < MIDG; c++) acc[c] = make_float2(0.f, 0.f);

    const float4* wl4 = (const float4*)wT;
#pragma unroll 4
    for (int ci = 0; ci < MIDG; ci++) {
        int csh = (int)g * MIDG + ci;              // shuffled channel index
        int c2 = (csh % 3) * 20 + csh / 3;         // source channel in t2
        float2 xv = *(const float2*)(t2 + ((size_t)(b * MID + c2)) * HWSZ + pos);
        int wbase = ((g * MIDG + ci) * COUTG + q * MIDG) / 4;  // float4 index
#pragma unroll
        for (int k4 = 0; k4 < 5; k4++) {
            float4 wv = wl4[wbase + k4];
            acc[k4 * 4 + 0].x += wv.x * xv.x; acc[k4 * 4 + 0].y += wv.x * xv.y;
            acc[k4 * 4 + 1].x += wv.y * xv.x; acc[k4 * 4 + 1].y += wv.y * xv.y;
            acc[k4 * 4 + 2].x += wv.z * xv.x; acc[k4 * 4 + 2].y += wv.z * xv.y;
            acc[k4 * 4 + 3].x += wv.w * xv.x; acc[k4 * 4 + 3].y += wv.w * xv.y;
        }
    }

#pragma unroll
    for (int co = 0; co < MIDG; co++) {
        int cg = (int)g * COUTG + (int)q * MIDG + co;
        float sc = s3[cg], sf = sh3[cg];
        float2 xr = *(const float2*)(x + ((size_t)(b * CIN + cg)) * HWSZ + pos);
        float2 o;
        o.x = fmaxf(acc[co].x * sc + sf, 0.f) + xr.x;
        o.y = fmaxf(acc[co].y * sc + sf, 0.f) + xr.y;
        *(float2*)(out + ((size_t)(b * COUT + cg)) * HWSZ + pos) = o;
    }
}

extern "C" void kernel_launch(void* const* d_in, const int* in_sizes, int n_in,
                              void* d_out, int out_size, void* d_ws, size_t ws_size,
                              hipStream_t stream) {
    const float* x  = (const float*)d_in[0];
    const float* w1 = (const float*)d_in[1];
    const float* g1 = (const float*)d_in[2];
    const float* b1 = (const float*)d_in[3];
    const float* m1 = (const float*)d_in[4];
    const float* v1 = (const float*)d_in[5];
    const float* w2 = (const float*)d_in[6];
    const float* g2 = (const float*)d_in[7];
    const float* b2 = (const float*)d_in[8];
    const float* m2 = (const float*)d_in[9];
    const float* v2 = (const float*)d_in[10];
    const float* w3 = (const float*)d_in[11];
    const float* g3 = (const float*)d_in[12];
    const float* b3 = (const float*)d_in[13];
    const float* m3 = (const float*)d_in[14];
    const float* v3 = (const float*)d_in[15];
    float* out = (float*)d_out;

    float* t1 = (float*)d_ws;                          // 32*60*3136 floats
    float* t2 = t1 + (size_t)NB * MID * HWSZ;          // 32*60*3136 floats

    // K1: 32*3*4*1568 items / 256 = 2352 blocks
    k1_conv1_bn_relu<<<2352, 256, 0, stream>>>(x, w1, g1, b1, m1, v1, t1);
    // K2: 32*60*784 / 256 = 5880 blocks
    k2_dw_bn<<<5880, 256, 0, stream>>>(t1, w2, g2, b2, m2, v2, t2);
    // K3: 32*3*4*1568 / 256 = 2352 blocks
    k3_shuffle_conv_bn_relu_res<<<2352, 256, 0, stream>>>(t2, w3, g3, b3, m3, v3, x, out);
}

// Round 3
// 89.060 us; speedup vs baseline: 1.3927x; 1.3927x over previous
//
#include <hip/hip_runtime.h>
#include <hip/hip_bf16.h>

#define HH 56
#define WW 56
#define HWSZ 3136          // 56*56
#define NB 32              // batch
#define CIN 240
#define MID 60
#define NG 3
#define CING 80            // Cin per group (conv1)
#define MIDG 20            // mid per group
#define COUT 240
#define COUTG 80           // Cout per group (conv3)
#define BN_EPS 1e-5f

// -------- Kernel 1: grouped 1x1 conv (240->60, G=3) + BN1 + ReLU --------
// One thread: one float4 of positions, 5 out-channels (q = item&3).
// Lanes 0-3 share the same x loads -> HW coalescer dedups (no extra HBM).
// 32*3*784*4 = 301056 threads = 1176 blocks.
__global__ __launch_bounds__(256) void k1_conv1_bn_relu(
        const float* __restrict__ x, const float* __restrict__ w1,
        const float* __restrict__ g1, const float* __restrict__ b1,
        const float* __restrict__ m1, const float* __restrict__ v1,
        float* __restrict__ t1) {
    __shared__ float wlds[MID * CING];   // 4800 floats, layout [co_glob][ci]
    __shared__ float s1[MID], sh1[MID];
    const int tid = threadIdx.x;
    for (int i = tid; i < MID * CING; i += 256) wlds[i] = w1[i];
    if (tid < MID) {
        float inv = g1[tid] * rsqrtf(v1[tid] + BN_EPS);
        s1[tid] = inv;
        sh1[tid] = b1[tid] - m1[tid] * inv;
    }
    __syncthreads();

    const int item = blockIdx.x * 256 + tid;       // < 301056
    const unsigned q  = (unsigned)item & 3u;       // out-channel quarter
    const unsigned pg = (unsigned)item >> 2;       // < 75264
    const unsigned p4 = pg % 784u;
    const unsigned bg = pg / 784u;
    const unsigned b = bg / 3u, g = bg % 3u;
    const int pos = (int)p4 * 4;

    const float4* xb = (const float4*)(x + ((size_t)(b * CIN + g * CING)) * HWSZ) + p4;
    // channel stride in float4 units = 784
    float4 acc[5];
#pragma unroll
    for (int c = 0; c < 5; c++) acc[c] = make_float4(0.f, 0.f, 0.f, 0.f);

    const float4* wl4 = (const float4*)wlds;       // [co_glob][ci4], 20 float4 per row
#pragma unroll 5
    for (int c4 = 0; c4 < CING / 4; c4++) {
        float4 xv0 = xb[(c4 * 4 + 0) * 784];
        float4 xv1 = xb[(c4 * 4 + 1) * 784];
        float4 xv2 = xb[(c4 * 4 + 2) * 784];
        float4 xv3 = xb[(c4 * 4 + 3) * 784];
#pragma unroll
        for (int co = 0; co < 5; co++) {
            float4 wv = wl4[(g * MIDG + q * 5 + co) * (CING / 4) + c4];
            acc[co].x += wv.x * xv0.x + wv.y * xv1.x + wv.z * xv2.x + wv.w * xv3.x;
            acc[co].y += wv.x * xv0.y + wv.y * xv1.y + wv.z * xv2.y + wv.w * xv3.y;
            acc[co].z += wv.x * xv0.z + wv.y * xv1.z + wv.z * xv2.z + wv.w * xv3.z;
            acc[co].w += wv.x * xv0.w + wv.y * xv1.w + wv.z * xv2.w + wv.w * xv3.w;
        }
    }

#pragma unroll
    for (int co = 0; co < 5; co++) {
        int ch = g * MIDG + q * 5 + co;
        float sc = s1[ch], sf = sh1[ch];
        float4 o;
        o.x = fmaxf(acc[co].x * sc + sf, 0.f);
        o.y = fmaxf(acc[co].y * sc + sf, 0.f);
        o.z = fmaxf(acc[co].z * sc + sf, 0.f);
        o.w = fmaxf(acc[co].w * sc + sf, 0.f);
        *(float4*)(t1 + ((size_t)(b * MID + ch)) * HWSZ + pos) = o;
    }
}

// -------- Kernel 2: depthwise 3x3 (pad 1) + BN2 --------
__global__ __launch_bounds__(256) void k2_dw_bn(
        const float* __restrict__ t1, const float* __restrict__ w2,
        const float* __restrict__ g2, const float* __restrict__ b2,
        const float* __restrict__ m2, const float* __restrict__ v2,
        float* __restrict__ t2) {
    const int item = blockIdx.x * 256 + threadIdx.x;   // < 32*60*784 = 1505280
    const unsigned bc = (unsigned)item / 784u;
    const unsigned p4 = (unsigned)item % 784u;
    const unsigned c = bc % (unsigned)MID;
    const int pos = (int)p4 * 4;
    const int h = pos / WW;
    const int w = pos % WW;                            // w in {0,4,...,52}

    const float* base = t1 + (size_t)bc * HWSZ;
    float k[9];
#pragma unroll
    for (int i = 0; i < 9; i++) k[i] = w2[c * 9 + i];

    float acc0 = 0.f, acc1 = 0.f, acc2 = 0.f, acc3 = 0.f;
#pragma unroll
    for (int dy = -1; dy <= 1; dy++) {
        int r = h + dy;
        if (r < 0 || r >= HH) continue;
        const float* row = base + r * WW + w;
        float4 mid4 = *(const float4*)row;
        float v0 = (w > 0) ? row[-1] : 0.f;
        float v5 = (w + 4 < WW) ? row[4] : 0.f;
        float va[6] = {v0, mid4.x, mid4.y, mid4.z, mid4.w, v5};
        const float k0 = k[(dy + 1) * 3 + 0];
        const float k1 = k[(dy + 1) * 3 + 1];
        const float k2 = k[(dy + 1) * 3 + 2];
        acc0 += k0 * va[0] + k1 * va[1] + k2 * va[2];
        acc1 += k0 * va[1] + k1 * va[2] + k2 * va[3];
        acc2 += k0 * va[2] + k1 * va[3] + k2 * va[4];
        acc3 += k0 * va[3] + k1 * va[4] + k2 * va[5];
    }

    float inv = g2[c] * rsqrtf(v2[c] + BN_EPS);
    float sf = b2[c] - m2[c] * inv;
    float4 o;
    o.x = acc0 * inv + sf;
    o.y = acc1 * inv + sf;
    o.z = acc2 * inv + sf;
    o.w = acc3 * inv + sf;
    *(float4*)(t2 + (size_t)bc * HWSZ + pos) = o;
}

// -------- Kernel 3: channel shuffle (folded) + grouped 1x1 (60->240, G=3)
//          + BN3 + ReLU + residual add --------
// One thread: one float4 of positions, 20 of its group's 80 out-channels (q = item&3).
// Lanes 0-3 share the same t2 loads -> dedup'd in the coalescer.
__global__ __launch_bounds__(256) void k3_shuffle_conv_bn_relu_res(
        const float* __restrict__ t2, const float* __restrict__ w3,
        const float* __restrict__ g3, const float* __restrict__ b3,
        const float* __restrict__ m3, const float* __restrict__ v3,
        const float* __restrict__ x, float* __restrict__ out) {
    __shared__ float wT[NG * MIDG * COUTG];  // [g][ci][co_g] : 4800 floats
    __shared__ float s3[COUT], sh3[COUT];
    const int tid = threadIdx.x;
    for (int i = tid; i < NG * MIDG * COUTG; i += 256) {
        int co_glob = i / MIDG;     // row of w3
        int ci = i % MIDG;
        int gg = co_glob / COUTG;
        int cg = co_glob % COUTG;
        wT[(gg * MIDG + ci) * COUTG + cg] = w3[i];
    }
    if (tid < COUT) {
        float inv = g3[tid] * rsqrtf(v3[tid] + BN_EPS);
        s3[tid] = inv;
        sh3[tid] = b3[tid] - m3[tid] * inv;
    }
    __syncthreads();

    const int item = blockIdx.x * 256 + tid;  // < 301056
    const unsigned q  = (unsigned)item & 3u;  // out-channel quarter
    const unsigned pg = (unsigned)item >> 2;
    const unsigned p4 = pg % 784u;
    const unsigned bg = pg / 784u;
    const unsigned b = bg / 3u, g = bg % 3u;
    const int pos = (int)p4 * 4;

    float4 acc[MIDG];
#pragma unroll
    for (int c = 0; c < MIDG; c++) acc[c] = make_float4(0.f, 0.f, 0.f, 0.f);

    const float4* wl4 = (const float4*)wT;
#pragma unroll 4
    for (int ci = 0; ci < MIDG; ci++) {
        int csh = (int)g * MIDG + ci;              // shuffled channel index
        int c2 = (csh % 3) * 20 + csh / 3;         // source channel in t2
        float4 xv = *(const float4*)(t2 + ((size_t)(b * MID + c2)) * HWSZ + pos);
        int wbase = ((g * MIDG + ci) * COUTG + q * MIDG) / 4;  // float4 index
#pragma unroll
        for (int k4 = 0; k4 < 5; k4++) {
            float4 wv = wl4[wbase + k4];
            acc[k4 * 4 + 0].x += wv.x * xv.x; acc[k4 * 4 + 0].y += wv.x * xv.y;
            acc[k4 * 4 + 0].z += wv.x * xv.z; acc[k4 * 4 + 0].w += wv.x * xv.w;
            acc[k4 * 4 + 1].x += wv.y * xv.x; acc[k4 * 4 + 1].y += wv.y * xv.y;
            acc[k4 * 4 + 1].z += wv.y * xv.z; acc[k4 * 4 + 1].w += wv.y * xv.w;
            acc[k4 * 4 + 2].x += wv.z * xv.x; acc[k4 * 4 + 2].y += wv.z * xv.y;
            acc[k4 * 4 + 2].z += wv.z * xv.z; acc[k4 * 4 + 2].w += wv.z * xv.w;
            acc[k4 * 4 + 3].x += wv.w * xv.x; acc[k4 * 4 + 3].y += wv.w * xv.y;
            acc[k4 * 4 + 3].z += wv.w * xv.z; acc[k4 * 4 + 3].w += wv.w * xv.w;
        }
    }

#pragma unroll
    for (int co = 0; co < MIDG; co++) {
        int cg = (int)g * COUTG + (int)q * MIDG + co;
        float sc = s3[cg], sf = sh3[cg];
        float4 xr = *(const float4*)(x + ((size_t)(b * CIN + cg)) * HWSZ + pos);
        float4 o;
        o.x = fmaxf(acc[co].x * sc + sf, 0.f) + xr.x;
        o.y = fmaxf(acc[co].y * sc + sf, 0.f) + xr.y;
        o.z = fmaxf(acc[co].z * sc + sf, 0.f) + xr.z;
        o.w = fmaxf(acc[co].w * sc + sf, 0.f) + xr.w;
        *(float4*)(out + ((size_t)(b * COUT + cg)) * HWSZ + pos) = o;
    }
}

extern "C" void kernel_launch(void* const* d_in, const int* in_sizes, int n_in,
                              void* d_out, int out_size, void* d_ws, size_t ws_size,
                              hipStream_t stream) {
    const float* x  = (const float*)d_in[0];
    const float* w1 = (const float*)d_in[1];
    const float* g1 = (const float*)d_in[2];
    const float* b1 = (const float*)d_in[3];
    const float* m1 = (const float*)d_in[4];
    const float* v1 = (const float*)d_in[5];
    const float* w2 = (const float*)d_in[6];
    const float* g2 = (const float*)d_in[7];
    const float* b2 = (const float*)d_in[8];
    const float* m2 = (const float*)d_in[9];
    const float* v2 = (const float*)d_in[10];
    const float* w3 = (const float*)d_in[11];
    const float* g3 = (const float*)d_in[12];
    const float* b3 = (const float*)d_in[13];
    const float* m3 = (const float*)d_in[14];
    const float* v3 = (const float*)d_in[15];
    float* out = (float*)d_out;

    float* t1 = (float*)d_ws;                          // 32*60*3136 floats
    float* t2 = t1 + (size_t)NB * MID * HWSZ;          // 32*60*3136 floats

    // K1: 301056 threads / 256 = 1176 blocks
    k1_conv1_bn_relu<<<1176, 256, 0, stream>>>(x, w1, g1, b1, m1, v1, t1);
    // K2: 32*60*784 / 256 = 5880 blocks
    k2_dw_bn<<<5880, 256, 0, stream>>>(t1, w2, g2, b2, m2, v2, t2);
    // K3: 301056 threads / 256 = 1176 blocks
    k3_shuffle_conv_bn_relu_res<<<1176, 256, 0, stream>>>(t2, w3, g3, b3, m3, v3, x, out);
}